// Round 4
// baseline (96.872 us; speedup 1.0000x reference)
//
#include <hip/hip_runtime.h>

#define NPTS 16384
#define TH 33.33f

typedef __attribute__((ext_vector_type(8)))  __bf16 bf16x8;
typedef __attribute__((ext_vector_type(16))) float  f32x16;
typedef __attribute__((ext_vector_type(16))) unsigned u32x16;

__device__ __forceinline__ unsigned short f2bf(float x) {
    unsigned u = __float_as_uint(x);
    u += 0x7FFFu + ((u >> 16) & 1u);
    return (unsigned short)(u >> 16);
}
__device__ __forceinline__ float bf2f(unsigned short h) {
    return __uint_as_float(((unsigned)h) << 16);
}
__device__ __forceinline__ unsigned umin_(unsigned a, unsigned b) { return a < b ? a : b; }

union UV { uint4 v; bf16x8 h; unsigned short s[8]; };

// ws: d2part float[4 db][64 rowblock][8 seg][256]  (2 MB) — write-once, no init/atomics.
// fragment map: elem = (g*32 + idx)*8 + j with k = g*8 + j (A/B symmetric, verified R2-R16)
// A k: [qh(3), ql(3), qh(2) | zh, 1,1,1, 1.0, 0,0,0]
// B k: [ph(3), ph(3), pl(2) | zl, -hp0,-hp1,-hp2, -32, 0,0,0]
// MFMA score s'' = q.p - hp - 32  (strictly negative)  ;  d^2 = 2*(hq - 32 - s'')
// Fold: scores all negative => float-max == uint-min on bits; umin chains (R18).
//
// === DIAGNOSIS LEDGER ===
// R18 (int fold) = NEUTRAL: folds already fused. Budget per CU-round: matrix ~35%,
//   non-MFMA VALU ~23%, LDS ~6% => ALL pipes <40% => LATENCY-BOUND.
//   (VALUBusy derived metric INCLUDES MFMA issue; 55% ~= 32% mfma + 23% valu.)
// R19 (qa/qb reg double-buffer) = FAILED: +32 live VGPRs at the (256,4) 128-reg cap
//   => scratch spill (WRITE_SIZE 2->34 MB, FETCH 3.1->11.8 MB, chamfer +9 us).
//   ILP-via-registers is CLOSED at 4 blocks/CU. Champion inner loop restored.
// R20 (this): TLP instead. (256,5): unified regs 52+32acc ~= 88 <= cap 102 (no spill
//   expected); LDS 5*32KB = 160KB exactly. 20 waves/CU (+25% slots), more decorrelated
//   block phases per SIMD to cover lgkmcnt + MFMA-result stalls.
// R17 (symmetric one-pass) = +25 us: inner-loop col-fold serialization >> MFMA savings.
//
// === FROZEN CHAMPION LEDGER (R2-R16) ===
// REGISTER: acc 32 + ~52 VGPR. >~30 more live regs spills (R10/R13/R14/R19).
// SCHEDULING: R15 unroll-2 / R16 shuffle-epilogue = +14 us (AGPR<->VGPR copy tax).
//   Keep LDS-scratch epilogue + unroll 1 loops. R9 manual staging pipeline = kept.
// R11: staging ds_write must be lane-consecutive-16B. R5/R7: no inline asm on MFMA results.
// TIMING: ~48 us fixed harness re-poison fill of ws (268 MB) inside dur_us, independent
//   of ws bytes used. Addressable budget = chamfer (40.7) + merge (~1.3).

#define FOLD2(MM, AA) { \
    f32x16 t0 = __builtin_amdgcn_mfma_f32_32x32x16_bf16(AA, q0, zc, 0, 0, 0); \
    f32x16 t1 = __builtin_amdgcn_mfma_f32_32x32x16_bf16(AA, q1, zc, 0, 0, 0); \
    _Pragma("unroll") for (int j = 0; j < 16; j++) \
        MM[j] = umin_(umin_(__float_as_uint(t0[j]), __float_as_uint(t1[j])), MM[j]); }

__device__ __forceinline__ void conv_store(unsigned short* lb, int k,
                                           float x, float y, float z) {
    float hp = 0.5f * fmaf(z, z, fmaf(y, y, x * x));
    unsigned short xh = f2bf(x), yh = f2bf(y), zh = f2bf(z);
    unsigned short xl = f2bf(x - bf2f(xh)), yl = f2bf(y - bf2f(yh)), zl = f2bf(z - bf2f(zh));
    float rr = hp;
    unsigned short h0 = f2bf(rr); rr -= bf2f(h0);
    unsigned short h1 = f2bf(rr); rr -= bf2f(h1);
    unsigned short h2 = f2bf(rr);
    UV c0, c1;
    c0.s[0]=xh; c0.s[1]=yh; c0.s[2]=zh; c0.s[3]=xh; c0.s[4]=yh; c0.s[5]=zh; c0.s[6]=xl; c0.s[7]=yl;
    c1.s[0]=zl; c1.s[1]=(unsigned short)(h0^0x8000); c1.s[2]=(unsigned short)(h1^0x8000);
    c1.s[3]=(unsigned short)(h2^0x8000);
    c1.s[4]=0xC200;                      // bf16(-32): bias product with A k12 = 1.0
    c1.s[5]=0; c1.s[6]=0; c1.s[7]=0;
    int t = k >> 5, pos = k & 31;
    *(uint4*)(lb + t * 512 + pos * 8)       = c0.v;   // lanes consecutive-16B: conflict-free
    *(uint4*)(lb + t * 512 + 256 + pos * 8) = c1.v;
}

// hoisted staging: loads issued BEFORE the pt loop (latency covered by folds),
// conversion + LDS write AFTER it. Points k=tid and k=tid+256 per thread.
#define LOAD_PTS(CC) { \
    const float* g0 = pp + (size_t)(seg * 2048 + (CC) * 512 + tid) * 3; \
    px0 = g0[0]; py0 = g0[1]; pz0 = g0[2]; \
    const float* g1 = g0 + 768; \
    px1 = g1[0]; py1 = g1[1]; pz1 = g1[2]; }

#define CONV_WRITE(BUF) { \
    unsigned short* lb = (unsigned short*)(smem + (BUF) * 16384); \
    conv_store(lb, tid,       px0, py0, pz0); \
    conv_store(lb, tid + 256, px1, py1, pz1); }

// LDS-scratch epilogue (R12 champion form): acc bits -> padded LDS -> per-lane row
// uint-min reduce (negative floats: smaller bits == larger float).
#define EPILOG(MM, P) { \
    unsigned* sc = scratch + wave * 1056; \
    _Pragma("unroll") for (int j = 0; j < 16; j++) { \
        int r0 = (j & 3) + 8 * (j >> 2) + 4 * g; sc[r0 * 33 + cc] = MM[j]; } \
    __syncthreads(); \
    const unsigned* sr = sc + cc * 33 + g * 16; \
    unsigned mx = 0xFF800000u; \
    _Pragma("unroll") for (int k = 0; k < 16; k++) mx = umin_(mx, sr[k]); \
    mx = umin_(mx, (unsigned)__shfl_xor((int)mx, 32, 64)); \
    if (lane < 32) { \
        float sbi = __uint_as_float(mx); \
        float d2 = 2.0f * (hq[P] - 32.0f - sbi); \
        float d = fminf(sqrtf(fmaxf(d2, 0.0f)), TH); \
        dst[wave * 64 + (P) * 32 + lane] = d; } \
    __syncthreads(); }

__global__ __launch_bounds__(256, 5) void chamfer_kernel(
        const float* __restrict__ src, const float* __restrict__ tgt,
        float* __restrict__ d2part, float* __restrict__ out)
{
    const int db = blockIdx.y, dir = db >> 1, b = db & 1;
    const int rowblock = blockIdx.x >> 3, seg = blockIdx.x & 7;   // 64 rowblocks x 8 segs
    const int tid = threadIdx.x, wave = tid >> 6, lane = tid & 63;
    const int g = lane >> 5, cc = lane & 31;
    if (blockIdx.x == 0 && db == 0 && tid < 2) out[tid] = 0.0f;   // replaces memset node
    const float* qp = (dir == 0 ? src : tgt) + (size_t)b * NPTS * 3;
    const float* pp = (dir == 0 ? tgt : src) + (size_t)b * NPTS * 3;
    const unsigned short one = 0x3F80;

    // 32 KB: two 16 KB stage buffers; aliased as epilogue scratch after the loop
    __shared__ alignas(16) unsigned char smem[32768];
    unsigned* scratch = (unsigned*)smem;  // 4 waves * 32 rows * 33 words = 16.9 KB

    // ---- A fragments + hq: 2 row-tiles (64 rows) per wave ----
    const int rt0 = rowblock * 8 + wave * 2;
    bf16x8 afrag[2]; float hq[2];
#pragma unroll
    for (int i = 0; i < 2; i++) {
        int r = (rt0 + i) * 32 + cc;
        float x = qp[r * 3 + 0], y = qp[r * 3 + 1], z = qp[r * 3 + 2];
        hq[i] = 0.5f * fmaf(z, z, fmaf(y, y, x * x));
        unsigned short xh = f2bf(x), yh = f2bf(y), zh = f2bf(z);
        unsigned short xl = f2bf(x - bf2f(xh)), yl = f2bf(y - bf2f(yh)), zl = f2bf(z - bf2f(zh));
        UV f0, f1, rv;
        f0.s[0]=xh; f0.s[1]=yh; f0.s[2]=zh; f0.s[3]=xl; f0.s[4]=yl; f0.s[5]=zl; f0.s[6]=xh; f0.s[7]=yh;
        f1.s[0]=zh; f1.s[1]=one; f1.s[2]=one; f1.s[3]=one;
        f1.s[4]=one;                      // k12: pairs with B's bf16(-32) bias slot
        f1.s[5]=0; f1.s[6]=0; f1.s[7]=0;
        rv.v = g ? f1.v : f0.v;
        afrag[i] = rv.h;
    }

    u32x16 m0 = 0xFF800000u, m1 = 0xFF800000u;   // bits of -inf: umin identity here
    const f32x16 zc = 0.0f;
    float px0, py0, pz0, px1, py1, pz1;

    LOAD_PTS(0)
    CONV_WRITE(0)
    __syncthreads();
#pragma unroll 1
    for (int c = 0; c < 4; ++c) {                 // 4 chunks x 16 col-tiles
        if (c < 3) LOAD_PTS(c + 1)                // issue loads; consumed after pt loop
        const unsigned short* bb = (const unsigned short*)(smem + (c & 1) * 16384);
#pragma unroll 1
        for (int pt = 0; pt < 8; ++pt) {          // 2 col-tiles per iter (champion shape)
            bf16x8 q0 = *(const bf16x8*)(bb + pt * 1024 + lane * 8);
            bf16x8 q1 = *(const bf16x8*)(bb + pt * 1024 + 512 + lane * 8);
            FOLD2(m0, afrag[0])
            FOLD2(m1, afrag[1])
        }
        if (c < 3) CONV_WRITE((c + 1) & 1)        // convert + stage after latency is hidden
        __syncthreads();
    }

    float* dst = d2part + (((size_t)(db * 64 + rowblock)) * 8 + seg) * 256;
    EPILOG(m0, 0)
    EPILOG(m1, 1)
}

__global__ __launch_bounds__(256) void merge_kernel(const float* __restrict__ d2part,
                                                    float* __restrict__ out) {
    const int b = blockIdx.y;                     // batch
    const int slice = blockIdx.x;                 // 16 slices of 1024 rows
    const int tid = threadIdx.x;
    float s = 0.0f;
#pragma unroll
    for (int pass = 0; pass < 2; pass++) {        // dir 0 and dir 1
        const float* base = d2part + (size_t)(pass * 2 + b) * 64 * 8 * 256;
#pragma unroll
        for (int i = 0; i < 4; i++) {
            int r = slice * 1024 + i * 256 + tid;
            const float* p = base + (size_t)(r >> 8) * 2048 + (r & 255);
            float m = p[0];
#pragma unroll
            for (int sgi = 1; sgi < 8; sgi++) m = fminf(m, p[sgi * 256]);
            s += m;
        }
    }
#pragma unroll
    for (int off = 32; off > 0; off >>= 1) s += __shfl_down(s, off, 64);
    __shared__ float w[4];
    if ((tid & 63) == 0) w[tid >> 6] = s;
    __syncthreads();
    if (tid == 0) {
        float t = (w[0] + w[1]) + (w[2] + w[3]);
        atomicAdd(&out[b], t * (1.0f / (2.0f * NPTS)));  // (mean_fwd + mean_bwd) / 2
    }
}

extern "C" void kernel_launch(void* const* d_in, const int* in_sizes, int n_in,
                              void* d_out, int out_size, void* d_ws, size_t ws_size,
                              hipStream_t stream) {
    const float* src = (const float*)d_in[0];
    const float* tgt = (const float*)d_in[1];
    float* out = (float*)d_out;
    float* d2part = (float*)d_ws;                 // 2 MB, write-once (no init needed)

    chamfer_kernel<<<dim3(512, 4), 256, 0, stream>>>(src, tgt, d2part, out);
    merge_kernel<<<dim3(16, 2), 256, 0, stream>>>(d2part, out);
}

// Round 5
// 96.683 us; speedup vs baseline: 1.0019x; 1.0019x over previous
//
#include <hip/hip_runtime.h>

#define NPTS 16384
#define TH 33.33f

typedef __attribute__((ext_vector_type(8)))  __bf16 bf16x8;
typedef __attribute__((ext_vector_type(16))) float  f32x16;
typedef __attribute__((ext_vector_type(16))) unsigned u32x16;

__device__ __forceinline__ unsigned short f2bf(float x) {
    unsigned u = __float_as_uint(x);
    u += 0x7FFFu + ((u >> 16) & 1u);
    return (unsigned short)(u >> 16);
}
__device__ __forceinline__ float bf2f(unsigned short h) {
    return __uint_as_float(((unsigned)h) << 16);
}
__device__ __forceinline__ unsigned umin_(unsigned a, unsigned b) { return a < b ? a : b; }

union UV { uint4 v; bf16x8 h; unsigned short s[8]; };

// ws: pfmt byte[4 set][16384 pt][32] (4 MB, prep output) + d2part float[4 db][128 rb][8 seg][128] (2 MB).
// fragment map: elem = (g*32 + idx)*8 + j with k = g*8 + j (verified R2-R16)
// A k: [qh(3), ql(3), qh(2) | zh, 1,1,1, 1.0, 0,0,0]
// B k: [ph(3), ph(3), pl(2) | zl, -hp0,-hp1,-hp2, -32, 0,0,0]
// score s'' = q.p - hp - 32 (strictly negative) ; d^2 = 2*(hq - 32 - s'')
// Fold: negative floats => float-max == uint-min on bits; umin3 chains (R18).
//
// === DIAGNOSIS LEDGER ===
// Per-MFMA cost recalibrated from m119: 32x32x16 bf16 ~= 32 cyc/SIMD (NOT 8). Champion
//   per-SIMD/round: matrix 16.5k cyc (=34% MfmaUtil ✓), fold 8.2k, staging ~5k vs wall
//   48.7k => wall ~= SUM of 4 waves' serial chains: convoy, waves not overlapping.
// R19 (qa/qb reg dbuf) = FAIL: +32 VGPR at 128-cap => scratch spill. ILP route closed.
// R20 ((256,5)) = FAIL: VGPR squeezed to 48 but Occupancy STILL 30% + spill traffic.
//   => occupancy quantum is POWER-OF-2: <=64 regs -> 8 waves/SIMD, <=128 -> 4. No 5/6/7.
// R21 (this): real TLP step. One 32-row tile/wave (acc 16), conv hoisted to prep_kernel
//   (pfmt 4 MB, L3-resident), pure-copy staging, single 16KB buffer + aliased scratch
//   (LDS 16.9KB => 8 blocks/CU), (256,8). Peak regs ~58 <= 64.
// R17 (symmetric one-pass) = +25 us: in-loop col-fold serialization >> MFMA savings.
// R18 (int fold) = NEUTRAL (folds already fused); kept for v_min3_u32 reliability.
//
// === FROZEN LEDGER (R2-R16) ===
// R11: staging ds_write lane-consecutive-16B. R5/R7: no inline asm on MFMA results.
// R15/R16: unroll-2 / shuffle-epilogue = +14us (AGPR<->VGPR copy tax). Keep unroll 1
//   + LDS-scratch epilogue.
// TIMING: dur_us includes fixed ~48us harness re-poison fill (268 MB), independent of
//   ws bytes used. Addressable budget = prep + chamfer + merge.

// ---- prep: convert all points of both tensors/batches to the 32B LDS-image format ----
// set: 0,1 = src[b] ; 2,3 = tgt[b].  point p -> offset (p>>5)*1024 + (p&31)*16 (+512 for c1)
__global__ __launch_bounds__(256) void prep_kernel(
        const float* __restrict__ src, const float* __restrict__ tgt,
        unsigned char* __restrict__ pfmt, float* __restrict__ out)
{
    const int set = blockIdx.y;                   // 4 sets
    const int chunk = blockIdx.x;                 // 64 chunks x 256 pts
    const int tid = threadIdx.x;
    if (set == 0 && chunk == 0 && tid < 2) out[tid] = 0.0f;   // replaces memset node
    const float* base = (set < 2 ? src : tgt) + (size_t)(set & 1) * NPTS * 3;
    const int p = chunk * 256 + tid;
    const float x = base[p * 3 + 0], y = base[p * 3 + 1], z = base[p * 3 + 2];

    float hp = 0.5f * fmaf(z, z, fmaf(y, y, x * x));
    unsigned short xh = f2bf(x), yh = f2bf(y), zh = f2bf(z);
    unsigned short xl = f2bf(x - bf2f(xh)), yl = f2bf(y - bf2f(yh)), zl = f2bf(z - bf2f(zh));
    float rr = hp;
    unsigned short h0 = f2bf(rr); rr -= bf2f(h0);
    unsigned short h1 = f2bf(rr); rr -= bf2f(h1);
    unsigned short h2 = f2bf(rr);
    UV c0, c1;
    c0.s[0]=xh; c0.s[1]=yh; c0.s[2]=zh; c0.s[3]=xh; c0.s[4]=yh; c0.s[5]=zh; c0.s[6]=xl; c0.s[7]=yl;
    c1.s[0]=zl; c1.s[1]=(unsigned short)(h0^0x8000); c1.s[2]=(unsigned short)(h1^0x8000);
    c1.s[3]=(unsigned short)(h2^0x8000);
    c1.s[4]=0xC200;                     // bf16(-32) bias, pairs with A k12 = 1.0
    c1.s[5]=0; c1.s[6]=0; c1.s[7]=0;

    unsigned char* ob = pfmt + (size_t)set * NPTS * 32
                             + (size_t)(p >> 5) * 1024 + (size_t)(p & 31) * 16;
    *(uint4*)(ob)       = c0.v;
    *(uint4*)(ob + 512) = c1.v;
}

__global__ __launch_bounds__(256, 8) void chamfer_kernel(
        const float* __restrict__ src, const float* __restrict__ tgt,
        const unsigned char* __restrict__ pfmt, float* __restrict__ d2part)
{
    const int db = blockIdx.y, dir = db >> 1, b = db & 1;
    const int rowblock = blockIdx.x >> 3, seg = blockIdx.x & 7;   // 128 rowblocks x 8 segs
    const int tid = threadIdx.x, wave = tid >> 6, lane = tid & 63;
    const int g = lane >> 5, cc = lane & 31;
    const float* qp = (dir == 0 ? src : tgt) + (size_t)b * NPTS * 3;
    const int pset = (dir == 0 ? 2 + b : b);
    const unsigned char* ps = pfmt + (size_t)pset * NPTS * 32 + (size_t)seg * 2048 * 32;
    const unsigned short one = 0x3F80;

    // 16 KB stage buffer; aliased as 16.9 KB epilogue scratch (4 waves * 1056 words)
    __shared__ alignas(16) unsigned char smem[16896];
    unsigned* scratch = (unsigned*)smem;

    // ---- A fragment + hq: ONE 32-row tile per wave (acc 16 regs) ----
    const int rt = rowblock * 4 + wave;
    bf16x8 afrag; float hq;
    {
        int r = rt * 32 + cc;
        float x = qp[r * 3 + 0], y = qp[r * 3 + 1], z = qp[r * 3 + 2];
        hq = 0.5f * fmaf(z, z, fmaf(y, y, x * x));
        unsigned short xh = f2bf(x), yh = f2bf(y), zh = f2bf(z);
        unsigned short xl = f2bf(x - bf2f(xh)), yl = f2bf(y - bf2f(yh)), zl = f2bf(z - bf2f(zh));
        UV f0, f1, rv;
        f0.s[0]=xh; f0.s[1]=yh; f0.s[2]=zh; f0.s[3]=xl; f0.s[4]=yl; f0.s[5]=zl; f0.s[6]=xh; f0.s[7]=yh;
        f1.s[0]=zh; f1.s[1]=one; f1.s[2]=one; f1.s[3]=one;
        f1.s[4]=one;                    // k12: pairs with B's bf16(-32) bias slot
        f1.s[5]=0; f1.s[6]=0; f1.s[7]=0;
        rv.v = g ? f1.v : f0.v;
        afrag = rv.h;
    }

    u32x16 m0 = 0xFF800000u;            // bits of -inf: umin identity here
    const f32x16 zc = 0.0f;

    // ---- stage chunk 0 (pure byte copy: pfmt image == LDS image) ----
    {
        const uint4* gsrc = (const uint4*)ps + tid * 4;
        uint4 a0 = gsrc[0], a1 = gsrc[1], a2 = gsrc[2], a3 = gsrc[3];
        uint4* lw = (uint4*)smem + tid * 4;
        lw[0] = a0; lw[1] = a1; lw[2] = a2; lw[3] = a3;   // lane-consecutive 16B (R11)
    }
    __syncthreads();
#pragma unroll 1
    for (int c = 0; c < 4; ++c) {                 // 4 chunks x 16 col-tiles
        const unsigned short* bb = (const unsigned short*)smem;
#pragma unroll 1
        for (int pt = 0; pt < 8; ++pt) {          // 2 col-tiles per iter
            bf16x8 q0 = *(const bf16x8*)(bb + pt * 1024 + lane * 8);
            bf16x8 q1 = *(const bf16x8*)(bb + pt * 1024 + 512 + lane * 8);
            f32x16 t0 = __builtin_amdgcn_mfma_f32_32x32x16_bf16(afrag, q0, zc, 0, 0, 0);
            f32x16 t1 = __builtin_amdgcn_mfma_f32_32x32x16_bf16(afrag, q1, zc, 0, 0, 0);
#pragma unroll
            for (int j = 0; j < 16; j++)
                m0[j] = umin_(umin_(__float_as_uint(t0[j]), __float_as_uint(t1[j])), m0[j]);
        }
        __syncthreads();                          // all waves done reading buffer
        if (c < 3) {
            const uint4* gsrc = (const uint4*)(ps + (size_t)(c + 1) * 16384) + tid * 4;
            uint4 a0 = gsrc[0], a1 = gsrc[1], a2 = gsrc[2], a3 = gsrc[3];
            uint4* lw = (uint4*)smem + tid * 4;
            lw[0] = a0; lw[1] = a1; lw[2] = a2; lw[3] = a3;
        }
        __syncthreads();                          // staged data visible to all waves
    }

    // ---- epilogue: acc bits -> padded LDS (per-wave private region) -> row reduce ----
    float* dst = d2part + (((size_t)(db * 128 + rowblock)) * 8 + seg) * 128;
    {
        unsigned* sc = scratch + wave * 1056;
#pragma unroll
        for (int j = 0; j < 16; j++) {
            int r0 = (j & 3) + 8 * (j >> 2) + 4 * g;
            sc[r0 * 33 + cc] = m0[j];
        }
        const unsigned* sr = sc + cc * 33 + g * 16;   // intra-wave dep: lgkmcnt orders it
        unsigned mx = 0xFF800000u;
#pragma unroll
        for (int k = 0; k < 16; k++) mx = umin_(mx, sr[k]);
        mx = umin_(mx, (unsigned)__shfl_xor((int)mx, 32, 64));
        if (lane < 32) {
            float sbi = __uint_as_float(mx);
            float d2 = 2.0f * (hq - 32.0f - sbi);
            float d = fminf(sqrtf(fmaxf(d2, 0.0f)), TH);
            dst[wave * 32 + lane] = d;
        }
    }
}

__global__ __launch_bounds__(256) void merge_kernel(const float* __restrict__ d2part,
                                                    float* __restrict__ out) {
    const int b = blockIdx.y;                     // batch
    const int slice = blockIdx.x;                 // 16 slices of 1024 rows
    const int tid = threadIdx.x;
    float s = 0.0f;
#pragma unroll
    for (int pass = 0; pass < 2; pass++) {        // dir 0 and dir 1
        const float* base = d2part + (size_t)(pass * 2 + b) * 128 * 8 * 128;
#pragma unroll
        for (int i = 0; i < 4; i++) {
            int r = slice * 1024 + i * 256 + tid;
            const float* p = base + (size_t)(r >> 7) * 1024 + (r & 127);
            float m = p[0];
#pragma unroll
            for (int sgi = 1; sgi < 8; sgi++) m = fminf(m, p[sgi * 128]);
            s += m;
        }
    }
#pragma unroll
    for (int off = 32; off > 0; off >>= 1) s += __shfl_down(s, off, 64);
    __shared__ float w[4];
    if ((tid & 63) == 0) w[tid >> 6] = s;
    __syncthreads();
    if (tid == 0) {
        float t = (w[0] + w[1]) + (w[2] + w[3]);
        atomicAdd(&out[b], t * (1.0f / (2.0f * NPTS)));  // (mean_fwd + mean_bwd) / 2
    }
}

extern "C" void kernel_launch(void* const* d_in, const int* in_sizes, int n_in,
                              void* d_out, int out_size, void* d_ws, size_t ws_size,
                              hipStream_t stream) {
    const float* src = (const float*)d_in[0];
    const float* tgt = (const float*)d_in[1];
    float* out = (float*)d_out;
    unsigned char* pfmt = (unsigned char*)d_ws;               // 4 MB
    float* d2part = (float*)(pfmt + (size_t)4 * 1024 * 1024); // 2 MB (ws >= 33 MB per R17 run)

    prep_kernel<<<dim3(64, 4), 256, 0, stream>>>(src, tgt, pfmt, out);
    chamfer_kernel<<<dim3(1024, 4), 256, 0, stream>>>(src, tgt, pfmt, d2part);
    merge_kernel<<<dim3(16, 2), 256, 0, stream>>>(d2part, out);
}